// Round 1
// baseline (4612.904 us; speedup 1.0000x reference)
//
#include <hip/hip_runtime.h>
#include <hip/hip_bf16.h>

// Problem constants
#define N_NODES 20000
#define KK 20
#define DD 128
#define HH 4
#define DKK 32
#define EE 128
#define HIDD 512
#define RTOT (N_NODES * KK)   // 400000 rows

using bf16 = __hip_bfloat16;

__device__ __forceinline__ float geluf(float x) {
    // exact gelu: 0.5*x*(1+erf(x/sqrt(2)))
    return 0.5f * x * (1.0f + erff(x * 0.70710678118654752f));
}

__device__ __forceinline__ float wave_sum(float v) {
#pragma unroll
    for (int o = 32; o > 0; o >>= 1) v += __shfl_down(v, o);
    return __shfl(v, 0);
}

// ---------------------------------------------------------------------------
// Kernel 1: z = node_h_src + gelu(edge_feat @ edge_fc_w + b) + cos((t_now-t)*freq+phase)
// Store z as bf16 into ws. Block = 128x8 (8 rows), grid = RTOT/8.
// ---------------------------------------------------------------------------
__global__ __launch_bounds__(1024)
void k1_msg(const float* __restrict__ nhs, const float* __restrict__ t,
            const float* __restrict__ t_now, const float* __restrict__ ef,
            const float* __restrict__ freq, const float* __restrict__ phase,
            const float* __restrict__ ew, const float* __restrict__ eb,
            bf16* __restrict__ z)
{
    __shared__ float efs[8][EE];
    const int tx = threadIdx.x;          // 0..127  (output col d / load col e)
    const int ty = threadIdx.y;          // 0..7    (row in block)
    const int row = blockIdx.x * 8 + ty; // < 400000
    efs[ty][tx] = ef[row * EE + tx];
    __syncthreads();

    float acc = eb[tx];
#pragma unroll 4
    for (int e = 0; e < EE; e++)
        acc += efs[ty][e] * ew[e * DD + tx];

    const float tn = t_now[0];
    const float tenc = cosf((tn - t[row]) * freq[tx] + phase[tx]);
    const float zz = nhs[row * DD + tx] + geluf(acc) + tenc;
    z[row * DD + tx] = __float2bfloat16(zz);
}

// ---------------------------------------------------------------------------
// Kernel 2: per-node attention block. Block = 256 threads, grid = N_NODES.
// q/k/v projections, self-slot override, 4-head attention over K=20,
// attn_fc + residual + LayerNorm. In-place update of ws rows (bf16).
// ---------------------------------------------------------------------------
__global__ __launch_bounds__(256)
void k2_attn(bf16* __restrict__ zx,
             const float* __restrict__ wq, const float* __restrict__ wk,
             const float* __restrict__ wv, const float* __restrict__ wqs,
             const float* __restrict__ afw, const float* __restrict__ afb,
             const float* __restrict__ lng, const float* __restrict__ lnb)
{
    __shared__ float z[KK][DD];       // 10 KB
    __shared__ float q[KK][DD];       // 10 KB (reused as attn-out "ao")
    __shared__ float kmat[KK][DD];    // 10 KB (reused as pre-LN "u")
    __shared__ float v[KK][DD];       // 10 KB
    __shared__ float sc[HH][KK][KK];  // 6.4 KB

    const int t = threadIdx.x;
    const int node = blockIdx.x;
    bf16* zrow = zx + node * KK * DD;

    for (int idx = t; idx < KK * DD; idx += 256)
        z[idx / DD][idx % DD] = __bfloat162float(zrow[idx]);
    __syncthreads();

    // --- QKV projections, register-blocked: thread (g,d) owns 10 rows, col d
    {
        const int g = t >> 7;          // 0/1 -> rows [0..9] / [10..19]
        const int d = t & 127;
        const int r0 = g * 10;
        float aq[10], ak[10], av[10];
#pragma unroll
        for (int r = 0; r < 10; r++) { aq[r] = 0.f; ak[r] = 0.f; av[r] = 0.f; }
        for (int e = 0; e < DD; e++) {
            const float wqv = wq[e * DD + d];
            const float wkv = wk[e * DD + d];
            const float wvv = wv[e * DD + d];
#pragma unroll
            for (int r = 0; r < 10; r++) {
                const float zv = z[r0 + r][e];
                aq[r] += zv * wqv;
                ak[r] += zv * wkv;
                av[r] += zv * wvv;
            }
        }
#pragma unroll
        for (int r = 0; r < 10; r++) {
            q[r0 + r][d] = aq[r];
            kmat[r0 + r][d] = ak[r];
            v[r0 + r][d] = av[r];
        }
    }
    __syncthreads();

    // --- self slot: q/k/v[19] = z[19] @ w_qs_src
    if (t < DD) {
        float a = 0.f;
#pragma unroll 4
        for (int e = 0; e < DD; e++) a += z[KK - 1][e] * wqs[e * DD + t];
        q[KK - 1][t] = a;
        kmat[KK - 1][t] = a;
        v[KK - 1][t] = a;
    }
    __syncthreads();

    // --- scores: sc[h][i][j] = (q_i . k_j)/sqrt(32)
    const float scale = 0.17677669529663687f; // 1/sqrt(32)
    for (int idx = t; idx < HH * KK * KK; idx += 256) {
        const int h = idx / (KK * KK);
        const int rem = idx % (KK * KK);
        const int i = rem / KK, j = rem % KK;
        float s = 0.f;
#pragma unroll
        for (int d = 0; d < DKK; d++)
            s += q[i][h * DKK + d] * kmat[j][h * DKK + d];
        sc[h][i][j] = s * scale;
    }
    __syncthreads();

    // --- softmax over j
    if (t < HH * KK) {
        const int h = t / KK, i = t % KK;
        float m = -1e30f;
#pragma unroll
        for (int j = 0; j < KK; j++) m = fmaxf(m, sc[h][i][j]);
        float s = 0.f;
#pragma unroll
        for (int j = 0; j < KK; j++) { const float e = __expf(sc[h][i][j] - m); sc[h][i][j] = e; s += e; }
        const float inv = 1.0f / s;
#pragma unroll
        for (int j = 0; j < KK; j++) sc[h][i][j] *= inv;
    }
    __syncthreads();

    // --- ao[i][c] = sum_j sc[h][i][j]*v[j][c]  (overwrite q)
    for (int idx = t; idx < KK * DD; idx += 256) {
        const int i = idx / DD, c = idx % DD, h = c / DKK;
        float o = 0.f;
#pragma unroll
        for (int j = 0; j < KK; j++) o += sc[h][i][j] * v[j][c];
        q[i][c] = o;  // careful: q no longer needed; all reads of q happened pre-barrier
    }
    __syncthreads();

    // --- attn_fc + residual into kmat (as u), register-blocked like qkv
    {
        const int g = t >> 7;
        const int d = t & 127;
        const int r0 = g * 10;
        float u[10];
#pragma unroll
        for (int r = 0; r < 10; r++) u[r] = afb[d];
        for (int c = 0; c < DD; c++) {
            const float wv2 = afw[c * DD + d];
#pragma unroll
            for (int r = 0; r < 10; r++) u[r] += q[r0 + r][c] * wv2;
        }
        __syncthreads();  // everyone done reading kmat (scores long done) before overwrite
#pragma unroll
        for (int r = 0; r < 10; r++) kmat[r0 + r][d] = u[r] + z[r0 + r][d];
    }
    __syncthreads();

    // --- LayerNorm per row, write bf16 in-place
    const int wid = t >> 6, lane = t & 63;
    for (int i = wid; i < KK; i += 4) {
        const float a0 = kmat[i][lane], a1 = kmat[i][lane + 64];
        const float s = wave_sum(a0 + a1);
        const float sq = wave_sum(a0 * a0 + a1 * a1);
        const float mean = s * (1.0f / DD);
        const float var = sq * (1.0f / DD) - mean * mean;
        const float inv = rsqrtf(var + 1e-5f);
        zrow[i * DD + lane]      = __float2bfloat16((a0 - mean) * inv * lng[lane] + lnb[lane]);
        zrow[i * DD + lane + 64] = __float2bfloat16((a1 - mean) * inv * lng[lane + 64] + lnb[lane + 64]);
    }
}

// ---------------------------------------------------------------------------
// Kernel 3: positionwise FFN (128->512 relu ->128) + residual + LN, in-place.
// Block = 256 threads, 16 rows per block, grid = RTOT/16.
// ---------------------------------------------------------------------------
__global__ __launch_bounds__(256)
void k3_ffn(bf16* __restrict__ zx,
            const float* __restrict__ w1, const float* __restrict__ b1,
            const float* __restrict__ w2, const float* __restrict__ b2,
            const float* __restrict__ lng, const float* __restrict__ lnb)
{
    __shared__ float xr[16][DD];    // 8 KB
    __shared__ float h1[16][HIDD];  // 32 KB
    __shared__ float u[16][DD];     // 8 KB

    const int t = threadIdx.x;
    const int base = blockIdx.x * 16 * DD;

    for (int idx = t; idx < 16 * DD; idx += 256)
        xr[idx / DD][idx % DD] = __bfloat162float(zx[base + idx]);
    __syncthreads();

    // --- phase A: h1 = relu(x @ W1 + b1). Thread owns cols {t, t+256}, all 16 rows.
    {
        const int j0 = t, j1 = t + 256;
        float a0[16], a1[16];
#pragma unroll
        for (int r = 0; r < 16; r++) { a0[r] = b1[j0]; a1[r] = b1[j1]; }
        for (int e = 0; e < DD; e++) {
            const float w0 = w1[e * HIDD + j0];
            const float wv = w1[e * HIDD + j1];
#pragma unroll
            for (int r = 0; r < 16; r++) {
                const float xv = xr[r][e];
                a0[r] += xv * w0;
                a1[r] += xv * wv;
            }
        }
#pragma unroll
        for (int r = 0; r < 16; r++) {
            h1[r][j0] = fmaxf(a0[r], 0.f);
            h1[r][j1] = fmaxf(a1[r], 0.f);
        }
    }
    __syncthreads();

    // --- phase B: u = h1 @ W2 + b2 + x. Thread (g,d) owns 8 rows, col d.
    {
        const int g = t >> 7;
        const int d = t & 127;
        const int r0 = g * 8;
        float acc[8];
#pragma unroll
        for (int r = 0; r < 8; r++) acc[r] = b2[d];
        for (int c = 0; c < HIDD; c++) {
            const float wv = w2[c * DD + d];
#pragma unroll
            for (int r = 0; r < 8; r++) acc[r] += h1[r0 + r][c] * wv;
        }
#pragma unroll
        for (int r = 0; r < 8; r++) u[r0 + r][d] = acc[r] + xr[r0 + r][d];
    }
    __syncthreads();

    // --- LN per row, write bf16 in-place
    const int wid = t >> 6, lane = t & 63;
    for (int r = wid; r < 16; r += 4) {
        const float a0 = u[r][lane], a1 = u[r][lane + 64];
        const float s = wave_sum(a0 + a1);
        const float sq = wave_sum(a0 * a0 + a1 * a1);
        const float mean = s * (1.0f / DD);
        const float var = sq * (1.0f / DD) - mean * mean;
        const float inv = rsqrtf(var + 1e-5f);
        zx[base + r * DD + lane]      = __float2bfloat16((a0 - mean) * inv * lng[lane] + lnb[lane]);
        zx[base + r * DD + lane + 64] = __float2bfloat16((a1 - mean) * inv * lng[lane + 64] + lnb[lane + 64]);
    }
}

// ---------------------------------------------------------------------------
// Kernel 4: fuse self + neighborhood mean, fea2node, gelu, residual, LN -> out
// Block = 128 threads, grid = N_NODES. Output fp32.
// ---------------------------------------------------------------------------
__global__ __launch_bounds__(128)
void k4_fuse(const bf16* __restrict__ zx, const float* __restrict__ nhs,
             const float* __restrict__ fw, const float* __restrict__ fb,
             const float* __restrict__ lng, const float* __restrict__ lnb,
             float* __restrict__ out)
{
    __shared__ float f[2 * DD];
    __shared__ float red[4];
    const int d = threadIdx.x;
    const int node = blockIdx.x;
    const bf16* xr = zx + node * KK * DD;

    float nb = 0.f;
#pragma unroll
    for (int i = 0; i < KK - 1; i++) nb += __bfloat162float(xr[i * DD + d]);
    f[d] = __bfloat162float(xr[(KK - 1) * DD + d]);
    f[DD + d] = nb * (1.0f / (KK - 1));
    __syncthreads();

    float a = fb[d];
#pragma unroll 4
    for (int c = 0; c < 2 * DD; c++) a += f[c] * fw[c * DD + d];
    const float y = geluf(a) + nhs[(node * KK + KK - 1) * DD + d];

    float s = y, sq = y * y;
#pragma unroll
    for (int o = 32; o > 0; o >>= 1) {
        s += __shfl_down(s, o);
        sq += __shfl_down(sq, o);
    }
    const int wid = d >> 6, lane = d & 63;
    if (lane == 0) { red[wid] = s; red[2 + wid] = sq; }
    __syncthreads();
    const float ts = red[0] + red[1], tsq = red[2] + red[3];
    const float mean = ts * (1.0f / DD);
    const float var = tsq * (1.0f / DD) - mean * mean;
    const float inv = rsqrtf(var + 1e-5f);
    out[node * DD + d] = (y - mean) * inv * lng[d] + lnb[d];
}

// ---------------------------------------------------------------------------
extern "C" void kernel_launch(void* const* d_in, const int* in_sizes, int n_in,
                              void* d_out, int out_size, void* d_ws, size_t ws_size,
                              hipStream_t stream)
{
    const float* nhs   = (const float*)d_in[0];
    const float* t     = (const float*)d_in[1];
    const float* tnow  = (const float*)d_in[2];
    const float* ef    = (const float*)d_in[3];
    const float* freq  = (const float*)d_in[4];
    const float* phase = (const float*)d_in[5];
    const float* ew    = (const float*)d_in[6];
    const float* eb    = (const float*)d_in[7];
    const float* wq    = (const float*)d_in[8];
    const float* wk    = (const float*)d_in[9];
    const float* wv    = (const float*)d_in[10];
    const float* wqs   = (const float*)d_in[11];
    const float* afw   = (const float*)d_in[12];
    const float* afb   = (const float*)d_in[13];
    const float* alng  = (const float*)d_in[14];
    const float* alnb  = (const float*)d_in[15];
    const float* w1    = (const float*)d_in[16];
    const float* b1    = (const float*)d_in[17];
    const float* w2    = (const float*)d_in[18];
    const float* b2    = (const float*)d_in[19];
    const float* flng  = (const float*)d_in[20];
    const float* flnb  = (const float*)d_in[21];
    const float* fw    = (const float*)d_in[22];
    const float* fb    = (const float*)d_in[23];
    const float* olng  = (const float*)d_in[24];
    const float* olnb  = (const float*)d_in[25];
    float* out = (float*)d_out;
    bf16* zx = (bf16*)d_ws;   // RTOT*DD bf16 = 102.4 MB, reused in-place per stage

    k1_msg<<<dim3(RTOT / 8), dim3(128, 8), 0, stream>>>(nhs, t, tnow, ef, freq, phase, ew, eb, zx);
    k2_attn<<<dim3(N_NODES), dim3(256), 0, stream>>>(zx, wq, wk, wv, wqs, afw, afb, alng, alnb);
    k3_ffn<<<dim3(RTOT / 16), dim3(256), 0, stream>>>(zx, w1, b1, w2, b2, flng, flnb);
    k4_fuse<<<dim3(N_NODES), dim3(128), 0, stream>>>(zx, nhs, fw, fb, olng, olnb, out);
}

// Round 2
// 3150.829 us; speedup vs baseline: 1.4640x; 1.4640x over previous
//
#include <hip/hip_runtime.h>
#include <hip/hip_bf16.h>

// Problem constants
#define N_NODES 20000
#define KK 20
#define DD 128
#define HH 4
#define DKK 32
#define EE 128
#define HIDD 512
#define RTOT (N_NODES * KK)   // 400000 rows

using bf16 = __hip_bfloat16;

typedef short s16x8 __attribute__((ext_vector_type(8)));   // 8 bf16 in 4 VGPRs
typedef float f32x4 __attribute__((ext_vector_type(4)));

__device__ __forceinline__ float geluf(float x) {
    return 0.5f * x * (1.0f + erff(x * 0.70710678118654752f));
}

__device__ __forceinline__ float wave_sum(float v) {
#pragma unroll
    for (int o = 32; o > 0; o >>= 1) v += __shfl_down(v, o);
    return __shfl(v, 0);
}

// ---------------------------------------------------------------------------
// Kernel 0: convert FFN weights to transposed bf16 [N][K] layout.
// w1t[n][k] = w1[k][n]  (512 x 128);  w2t[n][k] = w2[k][n]  (128 x 512)
// ---------------------------------------------------------------------------
__global__ __launch_bounds__(256)
void k0_conv(const float* __restrict__ w1, const float* __restrict__ w2,
             bf16* __restrict__ w1t, bf16* __restrict__ w2t)
{
    const int id = blockIdx.x * 256 + threadIdx.x;   // 0 .. 131071
    if (id < HIDD * DD) {
        const int n = id / DD, k = id % DD;          // w1t[n][k]
        w1t[id] = __float2bfloat16(w1[k * HIDD + n]);
    } else {
        const int j = id - HIDD * DD;                // w2t: n<128, k<512
        const int n = j / HIDD, k = j % HIDD;
        w2t[j] = __float2bfloat16(w2[k * DD + n]);
    }
}

// ---------------------------------------------------------------------------
// Kernel 1: z = node_h_src + gelu(edge_feat @ edge_fc_w + b) + cos((t_now-t)*freq+phase)
// ---------------------------------------------------------------------------
__global__ __launch_bounds__(1024)
void k1_msg(const float* __restrict__ nhs, const float* __restrict__ t,
            const float* __restrict__ t_now, const float* __restrict__ ef,
            const float* __restrict__ freq, const float* __restrict__ phase,
            const float* __restrict__ ew, const float* __restrict__ eb,
            bf16* __restrict__ z)
{
    __shared__ float efs[8][EE];
    const int tx = threadIdx.x;          // 0..127
    const int ty = threadIdx.y;          // 0..7
    const int row = blockIdx.x * 8 + ty;
    efs[ty][tx] = ef[row * EE + tx];
    __syncthreads();

    float acc = eb[tx];
#pragma unroll 4
    for (int e = 0; e < EE; e++)
        acc += efs[ty][e] * ew[e * DD + tx];

    const float tn = t_now[0];
    const float tenc = cosf((tn - t[row]) * freq[tx] + phase[tx]);
    const float zz = nhs[row * DD + tx] + geluf(acc) + tenc;
    z[row * DD + tx] = __float2bfloat16(zz);
}

// ---------------------------------------------------------------------------
// Kernel 2: per-node attention block (unchanged this round).
// ---------------------------------------------------------------------------
__global__ __launch_bounds__(256)
void k2_attn(bf16* __restrict__ zx,
             const float* __restrict__ wq, const float* __restrict__ wk,
             const float* __restrict__ wv, const float* __restrict__ wqs,
             const float* __restrict__ afw, const float* __restrict__ afb,
             const float* __restrict__ lng, const float* __restrict__ lnb)
{
    __shared__ float z[KK][DD];
    __shared__ float q[KK][DD];
    __shared__ float kmat[KK][DD];
    __shared__ float v[KK][DD];
    __shared__ float sc[HH][KK][KK];

    const int t = threadIdx.x;
    const int node = blockIdx.x;
    bf16* zrow = zx + node * KK * DD;

    for (int idx = t; idx < KK * DD; idx += 256)
        z[idx / DD][idx % DD] = __bfloat162float(zrow[idx]);
    __syncthreads();

    {
        const int g = t >> 7;
        const int d = t & 127;
        const int r0 = g * 10;
        float aq[10], ak[10], av[10];
#pragma unroll
        for (int r = 0; r < 10; r++) { aq[r] = 0.f; ak[r] = 0.f; av[r] = 0.f; }
        for (int e = 0; e < DD; e++) {
            const float wqv = wq[e * DD + d];
            const float wkv = wk[e * DD + d];
            const float wvv = wv[e * DD + d];
#pragma unroll
            for (int r = 0; r < 10; r++) {
                const float zv = z[r0 + r][e];
                aq[r] += zv * wqv;
                ak[r] += zv * wkv;
                av[r] += zv * wvv;
            }
        }
#pragma unroll
        for (int r = 0; r < 10; r++) {
            q[r0 + r][d] = aq[r];
            kmat[r0 + r][d] = ak[r];
            v[r0 + r][d] = av[r];
        }
    }
    __syncthreads();

    if (t < DD) {
        float a = 0.f;
#pragma unroll 4
        for (int e = 0; e < DD; e++) a += z[KK - 1][e] * wqs[e * DD + t];
        q[KK - 1][t] = a;
        kmat[KK - 1][t] = a;
        v[KK - 1][t] = a;
    }
    __syncthreads();

    const float scale = 0.17677669529663687f;
    for (int idx = t; idx < HH * KK * KK; idx += 256) {
        const int h = idx / (KK * KK);
        const int rem = idx % (KK * KK);
        const int i = rem / KK, j = rem % KK;
        float s = 0.f;
#pragma unroll
        for (int d = 0; d < DKK; d++)
            s += q[i][h * DKK + d] * kmat[j][h * DKK + d];
        sc[h][i][j] = s * scale;
    }
    __syncthreads();

    if (t < HH * KK) {
        const int h = t / KK, i = t % KK;
        float m = -1e30f;
#pragma unroll
        for (int j = 0; j < KK; j++) m = fmaxf(m, sc[h][i][j]);
        float s = 0.f;
#pragma unroll
        for (int j = 0; j < KK; j++) { const float e = __expf(sc[h][i][j] - m); sc[h][i][j] = e; s += e; }
        const float inv = 1.0f / s;
#pragma unroll
        for (int j = 0; j < KK; j++) sc[h][i][j] *= inv;
    }
    __syncthreads();

    for (int idx = t; idx < KK * DD; idx += 256) {
        const int i = idx / DD, c = idx % DD, h = c / DKK;
        float o = 0.f;
#pragma unroll
        for (int j = 0; j < KK; j++) o += sc[h][i][j] * v[j][c];
        q[i][c] = o;
    }
    __syncthreads();

    {
        const int g = t >> 7;
        const int d = t & 127;
        const int r0 = g * 10;
        float u[10];
#pragma unroll
        for (int r = 0; r < 10; r++) u[r] = afb[d];
        for (int c = 0; c < DD; c++) {
            const float wv2 = afw[c * DD + d];
#pragma unroll
            for (int r = 0; r < 10; r++) u[r] += q[r0 + r][c] * wv2;
        }
        __syncthreads();
#pragma unroll
        for (int r = 0; r < 10; r++) kmat[r0 + r][d] = u[r] + z[r0 + r][d];
    }
    __syncthreads();

    const int wid = t >> 6, lane = t & 63;
    for (int i = wid; i < KK; i += 4) {
        const float a0 = kmat[i][lane], a1 = kmat[i][lane + 64];
        const float s = wave_sum(a0 + a1);
        const float sq = wave_sum(a0 * a0 + a1 * a1);
        const float mean = s * (1.0f / DD);
        const float var = sq * (1.0f / DD) - mean * mean;
        const float inv = rsqrtf(var + 1e-5f);
        zrow[i * DD + lane]      = __float2bfloat16((a0 - mean) * inv * lng[lane] + lnb[lane]);
        zrow[i * DD + lane + 64] = __float2bfloat16((a1 - mean) * inv * lng[lane + 64] + lnb[lane + 64]);
    }
}

// ---------------------------------------------------------------------------
// Kernel 3: FFN via bf16 MFMA. 32 rows/block, 4 waves.
//   phase A: h1 = relu(x @ W1 + b1)    x:[32,128] W1t:[512,128] -> h1:[32,512] bf16 LDS
//   phase B: u  = h1 @ W2 + b2 + x     W2t:[128,512]
//   then rowwise LayerNorm, write bf16 in-place.
// MFMA 16x16x32 bf16. A[m=lane&15][k=quad*8+j]; B[k=quad*8+j][n=lane&15];
// D[row=quad*4+reg][col=lane&15]. LDS rows padded +8 bf16 -> 2-way bank alias (free).
// ---------------------------------------------------------------------------
#define XPAD (DD + 8)      // 136
#define HPAD (HIDD + 8)    // 520

__global__ __launch_bounds__(256)
void k3_ffn(bf16* __restrict__ zx,
            const bf16* __restrict__ w1t, const float* __restrict__ b1,
            const bf16* __restrict__ w2t, const float* __restrict__ b2,
            const float* __restrict__ lng, const float* __restrict__ lnb)
{
    __shared__ bf16 xs[32][XPAD];     // 8.5 KB
    __shared__ bf16 h1[32][HPAD];     // 32.5 KB ; reused as float u[32][128] after barrier

    const int t    = threadIdx.x;
    const int wv   = t >> 6;          // wave 0..3
    const int lane = t & 63;
    const int col  = lane & 15;
    const int quad = lane >> 4;       // 0..3
    const int base = blockIdx.x * 32 * DD;

    // --- stage x tile (32x128 bf16 = 8 KB), vectorized, pad-aware
    {
        const uint4* src = (const uint4*)(zx + base);   // 512 uint4
#pragma unroll
        for (int it = 0; it < 2; it++) {
            const int i = t + it * 256;                  // chunk of 8 bf16
            const int r = i >> 4, c = (i & 15) * 8;
            *(uint4*)&xs[r][c] = src[i];
        }
    }
    __syncthreads();

    // --- phase A: wave wv computes h1 cols [wv*128, wv*128+128)
    {
        f32x4 acc[2][8];
#pragma unroll
        for (int mt = 0; mt < 2; mt++)
#pragma unroll
            for (int nt = 0; nt < 8; nt++) acc[mt][nt] = (f32x4){0.f, 0.f, 0.f, 0.f};

#pragma unroll
        for (int kk = 0; kk < 4; kk++) {
            const int k0 = kk * 32 + quad * 8;
            const s16x8 a0 = *(const s16x8*)&xs[col][k0];
            const s16x8 a1 = *(const s16x8*)&xs[16 + col][k0];
#pragma unroll
            for (int nt = 0; nt < 8; nt++) {
                const int n = wv * 128 + nt * 16 + col;
                const s16x8 b = *(const s16x8*)&w1t[n * DD + k0];
                acc[0][nt] = __builtin_amdgcn_mfma_f32_16x16x32_bf16(a0, b, acc[0][nt], 0, 0, 0);
                acc[1][nt] = __builtin_amdgcn_mfma_f32_16x16x32_bf16(a1, b, acc[1][nt], 0, 0, 0);
            }
        }
#pragma unroll
        for (int nt = 0; nt < 8; nt++) {
            const int n = wv * 128 + nt * 16 + col;
            const float bias = b1[n];
#pragma unroll
            for (int r = 0; r < 4; r++) {
                const int row = quad * 4 + r;
                h1[row][n]      = __float2bfloat16(fmaxf(acc[0][nt][r] + bias, 0.f));
                h1[16 + row][n] = __float2bfloat16(fmaxf(acc[1][nt][r] + bias, 0.f));
            }
        }
    }
    __syncthreads();

    // --- phase B: wave wv computes u cols [wv*32, wv*32+32)
    {
        f32x4 acc[2][2];
#pragma unroll
        for (int mt = 0; mt < 2; mt++)
#pragma unroll
            for (int nt = 0; nt < 2; nt++) acc[mt][nt] = (f32x4){0.f, 0.f, 0.f, 0.f};

#pragma unroll 4
        for (int kk = 0; kk < 16; kk++) {
            const int k0 = kk * 32 + quad * 8;
            const s16x8 a0 = *(const s16x8*)&h1[col][k0];
            const s16x8 a1 = *(const s16x8*)&h1[16 + col][k0];
#pragma unroll
            for (int nt = 0; nt < 2; nt++) {
                const int n = wv * 32 + nt * 16 + col;
                const s16x8 b = *(const s16x8*)&w2t[n * HIDD + k0];
                acc[0][nt] = __builtin_amdgcn_mfma_f32_16x16x32_bf16(a0, b, acc[0][nt], 0, 0, 0);
                acc[1][nt] = __builtin_amdgcn_mfma_f32_16x16x32_bf16(a1, b, acc[1][nt], 0, 0, 0);
            }
        }
        __syncthreads();   // all waves done reading h1; safe to overwrite as u

        float* u = (float*)&h1[0][0];   // [32][128]
#pragma unroll
        for (int mt = 0; mt < 2; mt++)
#pragma unroll
            for (int nt = 0; nt < 2; nt++) {
                const int n = wv * 32 + nt * 16 + col;
                const float bias = b2[n];
#pragma unroll
                for (int r = 0; r < 4; r++) {
                    const int row = mt * 16 + quad * 4 + r;
                    u[row * DD + n] = acc[mt][nt][r] + bias + __bfloat162float(xs[row][n]);
                }
            }
    }
    __syncthreads();

    // --- LayerNorm per row, write bf16 in-place
    {
        const float* u = (const float*)&h1[0][0];
        for (int r = wv; r < 32; r += 4) {
            const float a0 = u[r * DD + lane], a1 = u[r * DD + lane + 64];
            const float s  = wave_sum(a0 + a1);
            const float sq = wave_sum(a0 * a0 + a1 * a1);
            const float mean = s * (1.0f / DD);
            const float var  = sq * (1.0f / DD) - mean * mean;
            const float inv  = rsqrtf(var + 1e-5f);
            zx[base + r * DD + lane]      = __float2bfloat16((a0 - mean) * inv * lng[lane] + lnb[lane]);
            zx[base + r * DD + lane + 64] = __float2bfloat16((a1 - mean) * inv * lng[lane + 64] + lnb[lane + 64]);
        }
    }
}

// ---------------------------------------------------------------------------
// Kernel 4: fuse self + neighborhood mean, fea2node, gelu, residual, LN -> out
// ---------------------------------------------------------------------------
__global__ __launch_bounds__(128)
void k4_fuse(const bf16* __restrict__ zx, const float* __restrict__ nhs,
             const float* __restrict__ fw, const float* __restrict__ fb,
             const float* __restrict__ lng, const float* __restrict__ lnb,
             float* __restrict__ out)
{
    __shared__ float f[2 * DD];
    __shared__ float red[4];
    const int d = threadIdx.x;
    const int node = blockIdx.x;
    const bf16* xr = zx + node * KK * DD;

    float nb = 0.f;
#pragma unroll
    for (int i = 0; i < KK - 1; i++) nb += __bfloat162float(xr[i * DD + d]);
    f[d] = __bfloat162float(xr[(KK - 1) * DD + d]);
    f[DD + d] = nb * (1.0f / (KK - 1));
    __syncthreads();

    float a = fb[d];
#pragma unroll 4
    for (int c = 0; c < 2 * DD; c++) a += f[c] * fw[c * DD + d];
    const float y = geluf(a) + nhs[(node * KK + KK - 1) * DD + d];

    float s = y, sq = y * y;
#pragma unroll
    for (int o = 32; o > 0; o >>= 1) {
        s += __shfl_down(s, o);
        sq += __shfl_down(sq, o);
    }
    const int wid = d >> 6, lane = d & 63;
    if (lane == 0) { red[wid] = s; red[2 + wid] = sq; }
    __syncthreads();
    const float ts = red[0] + red[1], tsq = red[2] + red[3];
    const float mean = ts * (1.0f / DD);
    const float var = tsq * (1.0f / DD) - mean * mean;
    const float inv = rsqrtf(var + 1e-5f);
    out[node * DD + d] = (y - mean) * inv * lng[d] + lnb[d];
}

// ---------------------------------------------------------------------------
extern "C" void kernel_launch(void* const* d_in, const int* in_sizes, int n_in,
                              void* d_out, int out_size, void* d_ws, size_t ws_size,
                              hipStream_t stream)
{
    const float* nhs   = (const float*)d_in[0];
    const float* t     = (const float*)d_in[1];
    const float* tnow  = (const float*)d_in[2];
    const float* ef    = (const float*)d_in[3];
    const float* freq  = (const float*)d_in[4];
    const float* phase = (const float*)d_in[5];
    const float* ew    = (const float*)d_in[6];
    const float* eb    = (const float*)d_in[7];
    const float* wq    = (const float*)d_in[8];
    const float* wk    = (const float*)d_in[9];
    const float* wv    = (const float*)d_in[10];
    const float* wqs   = (const float*)d_in[11];
    const float* afw   = (const float*)d_in[12];
    const float* afb   = (const float*)d_in[13];
    const float* alng  = (const float*)d_in[14];
    const float* alnb  = (const float*)d_in[15];
    const float* w1    = (const float*)d_in[16];
    const float* b1    = (const float*)d_in[17];
    const float* w2    = (const float*)d_in[18];
    const float* b2    = (const float*)d_in[19];
    const float* flng  = (const float*)d_in[20];
    const float* flnb  = (const float*)d_in[21];
    const float* fw    = (const float*)d_in[22];
    const float* fb    = (const float*)d_in[23];
    const float* olng  = (const float*)d_in[24];
    const float* olnb  = (const float*)d_in[25];
    float* out = (float*)d_out;

    bf16* zx  = (bf16*)d_ws;                                   // 102,400,000 B
    bf16* w1t = (bf16*)((char*)d_ws + (size_t)RTOT * DD * 2);  // +131072 B  [512][128]
    bf16* w2t = w1t + HIDD * DD;                               // +131072 B  [128][512]

    k0_conv<<<dim3(2 * HIDD * DD / 256), dim3(256), 0, stream>>>(w1, w2, w1t, w2t);
    k1_msg<<<dim3(RTOT / 8), dim3(128, 8), 0, stream>>>(nhs, t, tnow, ef, freq, phase, ew, eb, zx);
    k2_attn<<<dim3(N_NODES), dim3(256), 0, stream>>>(zx, wq, wk, wv, wqs, afw, afb, alng, alnb);
    k3_ffn<<<dim3(RTOT / 32), dim3(256), 0, stream>>>(zx, w1t, b1, w2t, b2, flng, flnb);
    k4_fuse<<<dim3(N_NODES), dim3(128), 0, stream>>>(zx, nhs, fw, fb, olng, olnb, out);
}